// Round 1
// baseline (224.102 us; speedup 1.0000x reference)
//
#include <hip/hip_runtime.h>
#include <math.h>

#define N 4096
#define B 2048
#define RANK 4
#define ALPHA 0.8862269254527580f   // sqrt(pi)/2
#define INV_N (1.0f / 4096.0f)

#define RPB1 8                      // rows per block, kernel 1
#define BLOCKS1 (N / RPB1)          // 512 blocks (2/CU, 16 waves/CU — proven BW config)
#define RPB3 4                      // rows per block, kernel 3

typedef float vf4 __attribute__((ext_vector_type(4)));

// Branchless Winitzki erf (max abs err ~2.5e-4; threshold is 0.24).
__device__ __forceinline__ float erf_fast(float t) {
  const float A = 0.140012288f;
  const float FP = 1.2732395447f;  // 4/pi
  float t2 = t * t;
  float num = fmaf(A, t2, FP);
  float den = fmaf(A, t2, 1.0f);
  float r = t2 * num * __builtin_amdgcn_rcpf(den);
  float e = __expf(-r);
  float s = __builtin_amdgcn_sqrtf(fmaxf(1.0f - e, 0.0f));
  return copysignf(s, t);
}

// ---------------------------------------------------------------------------
// Kernel 1: rank-4 (+z) reduction, fp32 HW atomics straight into sacc[5][B].
// 512 blocks x 512 thr. Block owns 8 whole rows = 64 KB contiguous slab of h;
// thread t owns cols 4t..4t+3; 8 unrolled vf4 loads; v/z via block-uniform
// (hoisted s_load) indices.
// Epilogue: 20 fire-and-forget global_atomic_add_f32 per thread. sacc is
// 40 KB -> LLC-resident; wave lanes cover 256 consecutive floats per plane
// (no intra-wave conflict); inter-block contention 512/address, ~<1 us chain
// smeared across the kernel. Replaces the 21 MB bf16 partials round trip AND
// the separate reduce kernel.
// ---------------------------------------------------------------------------
__global__ __launch_bounds__(512) void k_phi_reduce_atomic(
    const float* __restrict__ h, const float* __restrict__ v,
    const float* __restrict__ z, float* __restrict__ sacc) {
  const int tid = threadIdx.x;
  const int row0 = blockIdx.x * RPB1;

  vf4 a0 = {0.f, 0.f, 0.f, 0.f};
  vf4 a1 = a0, a2 = a0, a3 = a0, a4 = a0;

  const float* hp = h + (size_t)row0 * B + tid * 4;
#pragma unroll
  for (int r = 0; r < RPB1; ++r) {
    const vf4 hv = *(const vf4*)(hp + (size_t)r * B);
    vf4 p;
    p.x = erf_fast(ALPHA * hv.x);
    p.y = erf_fast(ALPHA * hv.y);
    p.z = erf_fast(ALPHA * hv.z);
    p.w = erf_fast(ALPHA * hv.w);
    const float v0 = v[(row0 + r) * RANK + 0];
    const float v1 = v[(row0 + r) * RANK + 1];
    const float v2 = v[(row0 + r) * RANK + 2];
    const float v3 = v[(row0 + r) * RANK + 3];
    const float zr = z[row0 + r];
    a0.x = fmaf(v0, p.x, a0.x); a0.y = fmaf(v0, p.y, a0.y);
    a0.z = fmaf(v0, p.z, a0.z); a0.w = fmaf(v0, p.w, a0.w);
    a1.x = fmaf(v1, p.x, a1.x); a1.y = fmaf(v1, p.y, a1.y);
    a1.z = fmaf(v1, p.z, a1.z); a1.w = fmaf(v1, p.w, a1.w);
    a2.x = fmaf(v2, p.x, a2.x); a2.y = fmaf(v2, p.y, a2.y);
    a2.z = fmaf(v2, p.z, a2.z); a2.w = fmaf(v2, p.w, a2.w);
    a3.x = fmaf(v3, p.x, a3.x); a3.y = fmaf(v3, p.y, a3.y);
    a3.z = fmaf(v3, p.z, a3.z); a3.w = fmaf(v3, p.w, a3.w);
    a4.x = fmaf(zr, p.x, a4.x); a4.y = fmaf(zr, p.y, a4.y);
    a4.z = fmaf(zr, p.z, a4.z); a4.w = fmaf(zr, p.w, a4.w);
  }

  float* sp = sacc + tid * 4;
  // unsafeAtomicAdd -> global_atomic_add_f32 (no CAS loop); result unused ->
  // no-return variant; device scope by default (works cross-XCD).
#define AADD(pl, acc)                        \
  unsafeAtomicAdd(sp + (pl) * B + 0, acc.x); \
  unsafeAtomicAdd(sp + (pl) * B + 1, acc.y); \
  unsafeAtomicAdd(sp + (pl) * B + 2, acc.z); \
  unsafeAtomicAdd(sp + (pl) * B + 3, acc.w);
  AADD(0, a0)
  AADD(1, a1)
  AADD(2, a2)
  AADD(3, a3)
  AADD(4, a4)
#undef AADD
}

// ---------------------------------------------------------------------------
// Kernel 3: h_new[n][b] = (sum_r u[n][r]*sfin[r][b])/N + m[n]*x[b]
// (DT/TAU = 1 -> h cancels exactly; h is never read.)
// 1024 blocks x 256 thr; block owns 4 whole rows = 32 KB contiguous
// nontemporal store slab. Thread t owns cols 4t and 4t+1024.
// Block 0 additionally emits y = sfin[4][:] / N (absorbed from old kernel 2).
// ---------------------------------------------------------------------------
__global__ __launch_bounds__(256) void k_update(
    const float* __restrict__ sfin, const float* __restrict__ u,
    const float* __restrict__ m, const float* __restrict__ x,
    float* __restrict__ y, float* __restrict__ hnew) {
  const int tid = threadIdx.x;
  const int row0 = blockIdx.x * RPB3;
  const int c0 = tid * 4;

  const vf4 sA0 = *(const vf4*)(sfin + 0 * B + c0);
  const vf4 sA1 = *(const vf4*)(sfin + 1 * B + c0);
  const vf4 sA2 = *(const vf4*)(sfin + 2 * B + c0);
  const vf4 sA3 = *(const vf4*)(sfin + 3 * B + c0);
  const vf4 xa  = *(const vf4*)(x + c0);
  const vf4 sB0 = *(const vf4*)(sfin + 0 * B + c0 + 1024);
  const vf4 sB1 = *(const vf4*)(sfin + 1 * B + c0 + 1024);
  const vf4 sB2 = *(const vf4*)(sfin + 2 * B + c0 + 1024);
  const vf4 sB3 = *(const vf4*)(sfin + 3 * B + c0 + 1024);
  const vf4 xb  = *(const vf4*)(x + c0 + 1024);

  if (blockIdx.x == 0) {
    vf4 ya = *(const vf4*)(sfin + 4 * B + c0);
    vf4 yb = *(const vf4*)(sfin + 4 * B + c0 + 1024);
    ya *= INV_N;
    yb *= INV_N;
    *(vf4*)(y + c0) = ya;
    *(vf4*)(y + c0 + 1024) = yb;
  }

  float* op = hnew + (size_t)row0 * B + c0;
#pragma unroll
  for (int i = 0; i < RPB3; ++i) {
    const int n = row0 + i;
    const vf4 uv = *(const vf4*)(u + (size_t)n * RANK);
    const float mv = m[n];
    vf4 oA, oB;
    oA.x = fmaf(mv, xa.x,
                (sA0.x * uv.x + sA1.x * uv.y + sA2.x * uv.z + sA3.x * uv.w) * INV_N);
    oA.y = fmaf(mv, xa.y,
                (sA0.y * uv.x + sA1.y * uv.y + sA2.y * uv.z + sA3.y * uv.w) * INV_N);
    oA.z = fmaf(mv, xa.z,
                (sA0.z * uv.x + sA1.z * uv.y + sA2.z * uv.z + sA3.z * uv.w) * INV_N);
    oA.w = fmaf(mv, xa.w,
                (sA0.w * uv.x + sA1.w * uv.y + sA2.w * uv.z + sA3.w * uv.w) * INV_N);
    oB.x = fmaf(mv, xb.x,
                (sB0.x * uv.x + sB1.x * uv.y + sB2.x * uv.z + sB3.x * uv.w) * INV_N);
    oB.y = fmaf(mv, xb.y,
                (sB0.y * uv.x + sB1.y * uv.y + sB2.y * uv.z + sB3.y * uv.w) * INV_N);
    oB.z = fmaf(mv, xb.z,
                (sB0.z * uv.x + sB1.z * uv.y + sB2.z * uv.z + sB3.z * uv.w) * INV_N);
    oB.w = fmaf(mv, xb.w,
                (sB0.w * uv.x + sB1.w * uv.y + sB2.w * uv.z + sB3.w * uv.w) * INV_N);
    __builtin_nontemporal_store(oA, (vf4*)(op + (size_t)i * B));
    __builtin_nontemporal_store(oB, (vf4*)(op + (size_t)i * B + 1024));
  }
}

// ---------------------------------------------------------------------------
extern "C" void kernel_launch(void* const* d_in, const int* in_sizes, int n_in,
                              void* d_out, int out_size, void* d_ws,
                              size_t ws_size, hipStream_t stream) {
  const float* x = (const float*)d_in[0];  // [1, B]
  const float* h = (const float*)d_in[1];  // [N, B]
  const float* m = (const float*)d_in[2];  // [N, 1]
  const float* u = (const float*)d_in[3];  // [N, RANK]
  const float* v = (const float*)d_in[4];  // [N, RANK]
  const float* z = (const float*)d_in[5];  // [N, 1]

  float* y = (float*)d_out;            // output 0: y [1, B]
  float* hnew = (float*)d_out + B;     // output 1: h_new [N, B]

  float* sacc = (float*)d_ws;          // [5][B] fp32 accumulator, 40 KB

  // Workspace is poisoned by the harness each iteration -> must re-zero the
  // atomic accumulator. Tiny memset node, graph-capturable.
  hipMemsetAsync(sacc, 0, (size_t)5 * B * sizeof(float), stream);
  k_phi_reduce_atomic<<<BLOCKS1, 512, 0, stream>>>(h, v, z, sacc);
  k_update<<<N / RPB3, 256, 0, stream>>>(sacc, u, m, x, y, hnew);
}

// Round 2
// 105.219 us; speedup vs baseline: 2.1299x; 2.1299x over previous
//
#include <hip/hip_runtime.h>
#include <math.h>

#define N 4096
#define B 2048
#define RANK 4
#define ALPHA 0.8862269254527580f   // sqrt(pi)/2
#define INV_N (1.0f / 4096.0f)

#define TR 64                       // tile rows (kernel 1)
#define TC 256                      // tile cols (kernel 1)
#define NSPLIT (N / TR)             // 64 fp32 partial splits (was 512 bf16)
#define CSTRIPES (B / TC)           // 8 col-stripes
#define PLANE (5 * B)               // one split = [5][B] floats
#define RPB3 4                      // rows per block, kernel 3

typedef float vf4 __attribute__((ext_vector_type(4)));

// Branchless Winitzki erf (max abs err ~2.5e-4; threshold is 0.24).
__device__ __forceinline__ float erf_fast(float t) {
  const float A = 0.140012288f;
  const float FP = 1.2732395447f;  // 4/pi
  float t2 = t * t;
  float num = fmaf(A, t2, FP);
  float den = fmaf(A, t2, 1.0f);
  float r = t2 * num * __builtin_amdgcn_rcpf(den);
  float e = __expf(-r);
  float s = __builtin_amdgcn_sqrtf(fmaxf(1.0f - e, 0.0f));
  return copysignf(s, t);
}

// ---------------------------------------------------------------------------
// Kernel 1: rank-4 (+z) partial reduction, 2D-tiled with LDS tree.
// 512 blocks (64 row-groups x 8 col-stripes) x 512 thr. Block owns a
// 64-row x 256-col tile of h; wave g owns 8 consecutive rows, lane l owns
// cols c0+4l..c0+4l+3 (each row read = 1 KB contiguous per wave). The 8
// waves' rank-4(+z) partials meet in a 40 KB LDS tree, so the global
// partials shrink to 64 splits of fp32 [5][B] = 2.6 MB total (vs the old
// 21 MB bf16 round trip), and accuracy improves (no bf16 quantization).
// v/z row indices are wave-uniform (readfirstlane) -> scalar loads.
// ---------------------------------------------------------------------------
__global__ __launch_bounds__(512) void k_phi_part(
    const float* __restrict__ h, const float* __restrict__ v,
    const float* __restrict__ z, float* __restrict__ partials) {
  __shared__ __align__(16) float red[5][8][TC];
  const int tid = threadIdx.x;
  const int l = tid & 63;
  const int g = tid >> 6;           // wave index, 0..7
  const int rg = blockIdx.x >> 3;   // row-group, 0..63
  const int cs = blockIdx.x & 7;    // col-stripe, 0..7
  const int r0 = rg * TR + g * 8;   // this wave's first row
  const int c0 = cs * TC;

  vf4 a0 = {0.f, 0.f, 0.f, 0.f};
  vf4 a1 = a0, a2 = a0, a3 = a0, a4 = a0;

  const float* hp = h + (size_t)r0 * B + c0 + l * 4;
#pragma unroll
  for (int r = 0; r < 8; ++r) {
    const vf4 hv = *(const vf4*)(hp + (size_t)r * B);
    vf4 p;
    p.x = erf_fast(ALPHA * hv.x);
    p.y = erf_fast(ALPHA * hv.y);
    p.z = erf_fast(ALPHA * hv.z);
    p.w = erf_fast(ALPHA * hv.w);
    const int row = __builtin_amdgcn_readfirstlane(r0 + r);  // wave-uniform
    const float v0 = v[row * RANK + 0];
    const float v1 = v[row * RANK + 1];
    const float v2 = v[row * RANK + 2];
    const float v3 = v[row * RANK + 3];
    const float zr = z[row];
    a0.x = fmaf(v0, p.x, a0.x); a0.y = fmaf(v0, p.y, a0.y);
    a0.z = fmaf(v0, p.z, a0.z); a0.w = fmaf(v0, p.w, a0.w);
    a1.x = fmaf(v1, p.x, a1.x); a1.y = fmaf(v1, p.y, a1.y);
    a1.z = fmaf(v1, p.z, a1.z); a1.w = fmaf(v1, p.w, a1.w);
    a2.x = fmaf(v2, p.x, a2.x); a2.y = fmaf(v2, p.y, a2.y);
    a2.z = fmaf(v2, p.z, a2.z); a2.w = fmaf(v2, p.w, a2.w);
    a3.x = fmaf(v3, p.x, a3.x); a3.y = fmaf(v3, p.y, a3.y);
    a3.z = fmaf(v3, p.z, a3.z); a3.w = fmaf(v3, p.w, a3.w);
    a4.x = fmaf(zr, p.x, a4.x); a4.y = fmaf(zr, p.y, a4.y);
    a4.z = fmaf(zr, p.z, a4.z); a4.w = fmaf(zr, p.w, a4.w);
  }

  // LDS tree: wave g deposits its 5 vf4 partials; conflict-free (contiguous
  // 16B per lane on write, stride-4B on read).
  *(vf4*)&red[0][g][l * 4] = a0;
  *(vf4*)&red[1][g][l * 4] = a1;
  *(vf4*)&red[2][g][l * 4] = a2;
  *(vf4*)&red[3][g][l * 4] = a3;
  *(vf4*)&red[4][g][l * 4] = a4;
  __syncthreads();

  // 5*TC = 1280 outputs, 512 threads: o = tid, tid+512, tid+1024(<256 only).
  for (int o = tid; o < 5 * TC; o += 512) {
    const int p = o >> 8;          // TC == 256
    const int c = o & (TC - 1);
    float s = 0.f;
#pragma unroll
    for (int g2 = 0; g2 < 8; ++g2) s += red[p][g2][c];
    partials[(size_t)rg * PLANE + p * B + c0 + c] = s;
  }
}

// ---------------------------------------------------------------------------
// Kernel 2: 64 fp32 splits -> sfin[4][B] + y[B]. 10 blocks x 256 thr; each
// thread owns one vf4 of the [5][B] plane, sums 64 splits (stride 40 KB,
// LLC-resident, unroll-8 independent loads).
// ---------------------------------------------------------------------------
__global__ __launch_bounds__(256) void k_reduce_final(
    const float* __restrict__ partials, float* __restrict__ sfin,
    float* __restrict__ y) {
  const int o4 = (blockIdx.x * 256 + threadIdx.x) * 4;  // 0..10236
  const float* pp = partials + o4;
  vf4 s = {0.f, 0.f, 0.f, 0.f};
#pragma unroll 8
  for (int sp = 0; sp < NSPLIT; ++sp)
    s += *(const vf4*)(pp + (size_t)sp * PLANE);
  if (o4 < RANK * B) {
    *(vf4*)(sfin + o4) = s;
  } else {
    s *= INV_N;                      // y = (z.T @ phi) / N
    *(vf4*)(y + (o4 - RANK * B)) = s;
  }
}

// ---------------------------------------------------------------------------
// Kernel 3: h_new[n][b] = (sum_r u[n][r]*sfin[r][b])/N + m[n]*x[b]
// (DT/TAU = 1 -> h cancels exactly; h is never read.)
// 1024 blocks x 256 thr; block owns 4 whole rows = 32 KB contiguous
// nontemporal store slab. Thread t owns cols 4t and 4t+1024.
// ---------------------------------------------------------------------------
__global__ __launch_bounds__(256) void k_update(
    const float* __restrict__ sfin, const float* __restrict__ u,
    const float* __restrict__ m, const float* __restrict__ x,
    float* __restrict__ hnew) {
  const int tid = threadIdx.x;
  const int row0 = blockIdx.x * RPB3;
  const int c0 = tid * 4;

  const vf4 sA0 = *(const vf4*)(sfin + 0 * B + c0);
  const vf4 sA1 = *(const vf4*)(sfin + 1 * B + c0);
  const vf4 sA2 = *(const vf4*)(sfin + 2 * B + c0);
  const vf4 sA3 = *(const vf4*)(sfin + 3 * B + c0);
  const vf4 xa  = *(const vf4*)(x + c0);
  const vf4 sB0 = *(const vf4*)(sfin + 0 * B + c0 + 1024);
  const vf4 sB1 = *(const vf4*)(sfin + 1 * B + c0 + 1024);
  const vf4 sB2 = *(const vf4*)(sfin + 2 * B + c0 + 1024);
  const vf4 sB3 = *(const vf4*)(sfin + 3 * B + c0 + 1024);
  const vf4 xb  = *(const vf4*)(x + c0 + 1024);

  float* op = hnew + (size_t)row0 * B + c0;
#pragma unroll
  for (int i = 0; i < RPB3; ++i) {
    const int n = row0 + i;
    const vf4 uv = *(const vf4*)(u + (size_t)n * RANK);
    const float mv = m[n];
    vf4 oA, oB;
    oA.x = fmaf(mv, xa.x,
                (sA0.x * uv.x + sA1.x * uv.y + sA2.x * uv.z + sA3.x * uv.w) * INV_N);
    oA.y = fmaf(mv, xa.y,
                (sA0.y * uv.x + sA1.y * uv.y + sA2.y * uv.z + sA3.y * uv.w) * INV_N);
    oA.z = fmaf(mv, xa.z,
                (sA0.z * uv.x + sA1.z * uv.y + sA2.z * uv.z + sA3.z * uv.w) * INV_N);
    oA.w = fmaf(mv, xa.w,
                (sA0.w * uv.x + sA1.w * uv.y + sA2.w * uv.z + sA3.w * uv.w) * INV_N);
    oB.x = fmaf(mv, xb.x,
                (sB0.x * uv.x + sB1.x * uv.y + sB2.x * uv.z + sB3.x * uv.w) * INV_N);
    oB.y = fmaf(mv, xb.y,
                (sB0.y * uv.x + sB1.y * uv.y + sB2.y * uv.z + sB3.y * uv.w) * INV_N);
    oB.z = fmaf(mv, xb.z,
                (sB0.z * uv.x + sB1.z * uv.y + sB2.z * uv.z + sB3.z * uv.w) * INV_N);
    oB.w = fmaf(mv, xb.w,
                (sB0.w * uv.x + sB1.w * uv.y + sB2.w * uv.z + sB3.w * uv.w) * INV_N);
    __builtin_nontemporal_store(oA, (vf4*)(op + (size_t)i * B));
    __builtin_nontemporal_store(oB, (vf4*)(op + (size_t)i * B + 1024));
  }
}

// ---------------------------------------------------------------------------
extern "C" void kernel_launch(void* const* d_in, const int* in_sizes, int n_in,
                              void* d_out, int out_size, void* d_ws,
                              size_t ws_size, hipStream_t stream) {
  const float* x = (const float*)d_in[0];  // [1, B]
  const float* h = (const float*)d_in[1];  // [N, B]
  const float* m = (const float*)d_in[2];  // [N, 1]
  const float* u = (const float*)d_in[3];  // [N, RANK]
  const float* v = (const float*)d_in[4];  // [N, RANK]
  const float* z = (const float*)d_in[5];  // [N, 1]

  float* y = (float*)d_out;            // output 0: y [1, B]
  float* hnew = (float*)d_out + B;     // output 1: h_new [N, B]

  float* partials = (float*)d_ws;                    // [64][5][B] fp32, 2.62 MB
  float* sfin = partials + (size_t)NSPLIT * PLANE;   // [RANK][B] fp32, 32 KB

  k_phi_part<<<NSPLIT * CSTRIPES, 512, 0, stream>>>(h, v, z, partials);
  k_reduce_final<<<PLANE / 1024, 256, 0, stream>>>(partials, sfin, y);
  k_update<<<N / RPB3, 256, 0, stream>>>(sfin, u, m, x, hnew);
}